// Round 6
// baseline (198.956 us; speedup 1.0000x reference)
//
#include <hip/hip_runtime.h>
#include <stdint.h>

typedef unsigned short u16;
typedef __attribute__((ext_vector_type(8))) short short8;   // 8 bf16 (4 VGPRs) — MFMA A/B frag
typedef __attribute__((ext_vector_type(4))) float float4v;  // MFMA C/D frag

__device__ __forceinline__ u16 f2bf(float f) {
    union { float f; uint32_t u; } v; v.f = f;
    uint32_t r = v.u + 0x7fffu + ((v.u >> 16) & 1u);  // RNE
    return (u16)(r >> 16);
}

__device__ __forceinline__ void gload16(const u16* g, u16* l) {
    __builtin_amdgcn_global_load_lds(
        (const __attribute__((address_space(1))) void*)g,
        (__attribute__((address_space(3))) void*)l, 16, 0, 0);
}

// s_waitcnt simm16 (gfx9/CDNA): vmcnt[3:0]|[15:14], expcnt[6:4], lgkmcnt[11:8]
#define WAITCNT_LGKM0  do { __builtin_amdgcn_s_waitcnt(0xC07F); asm volatile("" ::: "memory"); } while (0)
#define WAITCNT_VM8    do { __builtin_amdgcn_s_waitcnt(0x0F78); asm volatile("" ::: "memory"); } while (0)
#define WAITCNT_VM0    do { __builtin_amdgcn_s_waitcnt(0x0F70); asm volatile("" ::: "memory"); } while (0)

// ---------------- fused prep (R2/R5-proven, unchanged) ----------------
__global__ __launch_bounds__(256) void prep_fused(
    const float* __restrict__ x, u16* __restrict__ xbf,
    const float* __restrict__ wts,
    const float* __restrict__ W0, const float* __restrict__ W1, const float* __restrict__ W2,
    u16* __restrict__ W0t, u16* __restrict__ W1t, u16* __restrict__ W2t,
    const float* __restrict__ b0, const float* __restrict__ b1, const float* __restrict__ b2,
    float* __restrict__ bm) {
    __shared__ float tile[32][33];
    const int b = blockIdx.x, tid = threadIdx.x;

    if (b < 4096) {                       // ---- x -> bf16 ----
        int i = (b * 256 + tid) * 4;
        float4 v = *(const float4*)(x + i);
        union { u16 s[4]; uint64_t q; } o;
        o.s[0] = f2bf(v.x); o.s[1] = f2bf(v.y); o.s[2] = f2bf(v.z); o.s[3] = f2bf(v.w);
        *(uint64_t*)(xbf + i) = o.q;
        return;
    }

    float wn[8]; float s = 0.f;
    #pragma unroll
    for (int e = 0; e < 8; ++e) { wn[e] = wts[e]; s += wn[e]; }
    const float inv = 1.0f / s;

    if (b < 6144) {                       // ---- weight merge + transpose ----
        const float* W; u16* Wt; int K, N, lb;
        if (b < 4608)      { W = W0; Wt = W0t; K = 512;  N = 1024; lb = b - 4096; }
        else if (b < 5632) { W = W1; Wt = W1t; K = 1024; N = 1024; lb = b - 4608; }
        else               { W = W2; Wt = W2t; K = 1024; N = 512;  lb = b - 5632; }
        const int ntiles = N >> 5;
        const int o0 = (lb % ntiles) * 32, i0 = (lb / ntiles) * 32;
        const int tx = tid & 31, ty = tid >> 5;
        #pragma unroll
        for (int s4 = 0; s4 < 4; ++s4) {
            int il = ty + s4 * 8;
            float acc = 0.f;
            #pragma unroll
            for (int e = 0; e < 8; ++e)
                acc += wn[e] * W[(size_t)e * K * N + (size_t)(i0 + il) * N + o0 + tx];
            tile[il][tx] = acc * inv;
        }
        __syncthreads();
        #pragma unroll
        for (int s4 = 0; s4 < 4; ++s4) {
            int ol = ty + s4 * 8;
            Wt[(size_t)(o0 + ol) * K + i0 + tx] = f2bf(tile[tx][ol]);
        }
        return;
    }

    int t = (b - 6144) * 256 + tid;       // ---- bias merge ----
    if (t >= 2560) return;
    const float* bp; int o, stride;
    if (t < 1024)      { bp = b0; o = t;        stride = 1024; }
    else if (t < 2048) { bp = b1; o = t - 1024; stride = 1024; }
    else               { bp = b2; o = t - 2048; stride = 512;  }
    float acc = 0.f;
    #pragma unroll
    for (int e = 0; e < 8; ++e) acc += wn[e] * bp[e * stride + o];
    bm[t] = acc * inv;
}

// ------------- barrier-free wave-autonomous GEMM + bias + PReLU -------------
// A [M,K] bf16 row-major, Bt [N,K] bf16. Block = 256 thr = 4 waves stacked in M;
// block tile 256(M) x 64(N); each WAVE owns 64x64 with a PRIVATE 16 KB LDS slice:
// [A0 4K][B0 4K][A1 4K][B1 4K], BK=32 double-buffered. NO __syncthreads anywhere —
// explicit s_waitcnt: lgkmcnt(0) before overwriting a buffer, vmcnt(8) steady-state
// (next tile's 8 gload_lds stay in flight across the wait; vmcnt never hits 0
// mid-loop — the AITER-style pipeline the 2-barrier structure cannot express).
// Swizzle (32-elem rows = 16 banks): LDS pos p of row r holds global chunk
// p ^ ((r>>1)&3); reader uses pos = quad ^ ((l16>>1)&3) -> all 8 bank-slots
// distinct per quad-group, residual 2-way = free (m136).
template <bool OUT_F32, int NN_LOG2>
__global__ __launch_bounds__(256, 2) void gemm_bias_prelu(
    const u16* __restrict__ A, const u16* __restrict__ Bt,
    const float* __restrict__ bias, const float* __restrict__ alpha,
    void* __restrict__ outp, int M, int N, int K) {
    __shared__ __align__(16) u16 smem[4 * 8192];   // 64 KB: 4 waves x 16 KB
    const int tid = threadIdx.x;
    const int lane = tid & 63, w = tid >> 6;

    const int xcd   = blockIdx.x & 7;              // M-slab per XCD for L2 reuse
    const int inner = blockIdx.x >> 3;
    const int bn    = inner & ((1 << NN_LOG2) - 1);
    const int bmb   = xcd * 4 + (inner >> NN_LOG2);
    const int m0    = bmb * 256 + w * 64;          // wave's 64 M-rows
    const int n0    = bn * 64;                     // wave's 64 N-cols

    // staging lane invariants: row rl = lane>>2 within 16-row group, pos = lane&3,
    // global chunk c = pos ^ ((rl>>1)&3) = (lane&3) ^ ((lane>>3)&3)
    const int rl = lane >> 2;
    const int cg = (lane & 3) ^ ((lane >> 3) & 3);
    const u16* Ag = A  + (size_t)(m0 + rl) * K + cg * 8;
    const u16* Bg = Bt + (size_t)(n0 + rl) * K + cg * 8;

    u16* slice = smem + w * 8192;                  // u16 units; 16 KB per wave
    // buf b: A at b*4096, B at b*4096+2048 (u16)
    const int l16 = lane & 15, quad = lane >> 4;
    const int xr2 = (l16 >> 1) & 3;

    float4v acc[4][4] = {};
    const int nk = K >> 5;                         // BK=32

    // prologue: stage tile 0 into buf0 (8 gloads in flight)
    #pragma unroll
    for (int j = 0; j < 4; ++j) {
        gload16(Ag + (size_t)(j * 16) * K, slice + j * 512 + lane * 8);
        gload16(Bg + (size_t)(j * 16) * K, slice + 2048 + j * 512 + lane * 8);
    }

    for (int kt = 0; kt < nk; ++kt) {
        const int cur = (kt & 1) * 4096;
        if (kt + 1 < nk) {
            const int nxt = ((kt + 1) & 1) * 4096;
            const size_t ko = (size_t)(kt + 1) * 32;
            WAITCNT_LGKM0;                         // prior reads of 'nxt' buffer done
            #pragma unroll
            for (int j = 0; j < 4; ++j) {
                gload16(Ag + (size_t)(j * 16) * K + ko, slice + nxt + j * 512 + lane * 8);
                gload16(Bg + (size_t)(j * 16) * K + ko, slice + nxt + 2048 + j * 512 + lane * 8);
            }
            WAITCNT_VM8;                           // wait only current tile's 8 (oldest)
        } else {
            WAITCNT_VM0;                           // last tile: drain
        }

        const short8* As8 = (const short8*)(slice + cur);
        const short8* Bs8 = (const short8*)(slice + cur + 2048);
        short8 af[4], bf[4];
        const int pos = quad ^ xr2;
        #pragma unroll
        for (int mi = 0; mi < 4; ++mi)
            af[mi] = As8[(mi * 16 + l16) * 4 + pos];
        #pragma unroll
        for (int ni = 0; ni < 4; ++ni)
            bf[ni] = Bs8[(ni * 16 + l16) * 4 + pos];
        #pragma unroll
        for (int mi = 0; mi < 4; ++mi)
            #pragma unroll
            for (int ni = 0; ni < 4; ++ni)
                acc[mi][ni] = __builtin_amdgcn_mfma_f32_16x16x32_bf16(
                    af[mi], bf[ni], acc[mi][ni], 0, 0, 0);
    }

    // epilogue: C/D layout col=lane&15, row=quad*4+reg  [m89/m91; R1-R5 proven]
    const int cbase = n0 + l16;
    float bv[4], av[4];
    #pragma unroll
    for (int ni = 0; ni < 4; ++ni) { bv[ni] = bias[cbase + ni * 16]; av[ni] = alpha[cbase + ni * 16]; }
    const int rbase = m0 + quad * 4;
    #pragma unroll
    for (int mi = 0; mi < 4; ++mi) {
        #pragma unroll
        for (int reg = 0; reg < 4; ++reg) {
            int r = rbase + mi * 16 + reg;
            #pragma unroll
            for (int ni = 0; ni < 4; ++ni) {
                float v = acc[mi][ni][reg] + bv[ni];
                v = v >= 0.f ? v : av[ni] * v;
                size_t idx = (size_t)r * N + cbase + ni * 16;
                if (OUT_F32) ((float*)outp)[idx] = v;
                else         ((u16*)outp)[idx] = f2bf(v);
            }
        }
    }
}

extern "C" void kernel_launch(void* const* d_in, const int* in_sizes, int n_in,
                              void* d_out, int out_size, void* d_ws, size_t ws_size,
                              hipStream_t stream) {
    const float* x   = (const float*)d_in[0];
    const float* wts = (const float*)d_in[1];
    const float* W0  = (const float*)d_in[2];
    const float* b0  = (const float*)d_in[3];
    const float* a0  = (const float*)d_in[4];
    const float* W1  = (const float*)d_in[5];
    const float* b1  = (const float*)d_in[6];
    const float* a1  = (const float*)d_in[7];
    const float* W2  = (const float*)d_in[8];
    const float* b2  = (const float*)d_in[9];
    const float* a2  = (const float*)d_in[10];
    float* out = (float*)d_out;

    char* ws = (char*)d_ws;
    u16*   xbf  = (u16*)ws;  ws += (size_t)8192 * 512 * 2;
    u16*   act1 = (u16*)ws;  ws += (size_t)8192 * 1024 * 2;
    u16*   act2 = (u16*)ws;  ws += (size_t)8192 * 1024 * 2;
    u16*   W0t  = (u16*)ws;  ws += (size_t)1024 * 512 * 2;
    u16*   W1t  = (u16*)ws;  ws += (size_t)1024 * 1024 * 2;
    u16*   W2t  = (u16*)ws;  ws += (size_t)512 * 1024 * 2;
    float* bm   = (float*)ws;  // 2560 floats

    prep_fused<<<6154, 256, 0, stream>>>(x, xbf, wts, W0, W1, W2, W0t, W1t, W2t,
                                         b0, b1, b2, bm);

    // grids: block tile 256(M) x 64(N); L0/L1: 32 M-blocks x 16 strips = 512;
    // L2: 32 x 8 = 256. xcd = bid&7.
    gemm_bias_prelu<false, 4><<<512, 256, 0, stream>>>(xbf,  W0t, bm,        a0, act1, 8192, 1024, 512);
    gemm_bias_prelu<false, 4><<<512, 256, 0, stream>>>(act1, W1t, bm + 1024, a1, act2, 8192, 1024, 1024);
    gemm_bias_prelu<true,  3><<<256, 256, 0, stream>>>(act2, W2t, bm + 2048, a2, out,  8192, 512, 1024);
}